// Round 3
// baseline (996.247 us; speedup 1.0000x reference)
//
#include <hip/hip_runtime.h>
#include <hip/hip_bf16.h>

#define NN 16384
#define DD 300
#define DP 320
#define RR 10
#define BB 1024
#define KK 64
#define NCH 32   // column/row chunks (N / 512)

typedef __attribute__((ext_vector_type(8))) short s8v;   // 8 bf16 (4 VGPRs)
typedef __attribute__((ext_vector_type(4))) float f4v;   // MFMA accumulator

__device__ __forceinline__ float hi_bf(unsigned d) { return __uint_as_float(d & 0xFFFF0000u); }
__device__ __forceinline__ float lo_bf(unsigned d) { return __uint_as_float(d << 16); }

// sorted-descending top-10 insert (max/min swap chain: 2 VALU per slot)
__device__ __forceinline__ void topk_insert(float (&lst)[10], float v) {
    if (v > lst[9]) {
        float cur = v;
        #pragma unroll
        for (int q = 0; q < 10; ++q) {
            float a  = lst[q];
            float mx = fmaxf(a, cur);
            cur      = fminf(a, cur);
            lst[q]   = mx;
        }
    }
}

__device__ __forceinline__ void gload_lds16(const void* g, void* l) {
#if __has_builtin(__builtin_amdgcn_global_load_lds)
    __builtin_amdgcn_global_load_lds(
        (const __attribute__((address_space(1))) void*)g,
        (__attribute__((address_space(3))) void*)l, 16, 0, 0);
#else
    // fallback: reg-staged copy to the same linear slot (lane*16)
    const int lane = threadIdx.x & 63;
    int4 v = *reinterpret_cast<const int4*>(g);
    *reinterpret_cast<int4*>((char*)l + lane * 16) = v;
#endif
}

// ---------------------------------------------------------------------------
// Kernel 1: Householder tower + L2 normalize + bf16 cast (padded to 320).
// ---------------------------------------------------------------------------
__global__ __launch_bounds__(256) void tower_kernel(
        const float* __restrict__ feat, const float* __restrict__ vs,
        __hip_bfloat16* __restrict__ out) {
    __shared__ float vsh[RR * DD];
    const int tid = threadIdx.x;
    for (int i = tid; i < RR * DD; i += 256) vsh[i] = vs[i];
    __syncthreads();

    const int lane = tid & 63;
    const int wave = tid >> 6;
    const int row  = blockIdx.x * 4 + wave;

    float h[5];
    #pragma unroll
    for (int j = 0; j < 5; ++j) {
        int d = lane + 64 * j;
        h[j] = (d < DD) ? feat[(size_t)row * DD + d] : 0.f;
    }

    #pragma unroll
    for (int r = 0; r < RR; ++r) {
        float vl[5];
        float hv = 0.f, vv = 0.f;
        #pragma unroll
        for (int j = 0; j < 5; ++j) {
            int d = lane + 64 * j;
            float v = (d < DD) ? vsh[r * DD + d] : 0.f;
            vl[j] = v;
            hv += h[j] * v;
            vv += v * v;
        }
        #pragma unroll
        for (int o = 32; o; o >>= 1) {
            hv += __shfl_xor(hv, o);
            vv += __shfl_xor(vv, o);
        }
        float coef = hv / vv;
        #pragma unroll
        for (int j = 0; j < 5; ++j) h[j] -= coef * vl[j];
    }

    float nn = 0.f;
    #pragma unroll
    for (int j = 0; j < 5; ++j) nn += h[j] * h[j];
    #pragma unroll
    for (int o = 32; o; o >>= 1) nn += __shfl_xor(nn, o);
    float scale = 1.f / fmaxf(sqrtf(nn), 1e-12f);

    #pragma unroll
    for (int j = 0; j < 5; ++j) {
        int d = lane + 64 * j;
        float val = (d < DD) ? h[j] * scale : 0.f;
        out[(size_t)row * DP + d] = __float2bfloat16(val);
    }
}

// ---------------------------------------------------------------------------
// Kernel 2: 512x512 sim region per block (grid 32x32), 16 inner 128x128 MFMA
// tiles. global_load_lds staging (linear dest, inverse-swizzled source),
// packed-bf16 swizzled sim tile, group-max-filtered scans.
// LDS: 32KB staging/simt union + 40KB lists = 73728 B -> 2 blocks/CU.
// ---------------------------------------------------------------------------
__global__ __launch_bounds__(512, 4) void sim_topk_kernel(
        const __hip_bfloat16* __restrict__ A,   // src_hn [N][320]
        const __hip_bfloat16* __restrict__ Bm,  // tgt_hn [N][320]
        float* __restrict__ rowcand,            // [N][NCH][10]
        float* __restrict__ colcand) {          // [N][NCH][10]
    // union: staging (Asub[128][64] | Bsub[128][64] bf16, unit-swizzled via
    // source) = 32768 B  |  simt (dword [128][64], unit-XOR-swizzled).
    __shared__ __align__(16) char u_lds[32768];
    __shared__ float rowlist[512][10];
    __shared__ float collist[512][10];

    __hip_bfloat16* Asub = (__hip_bfloat16*)u_lds;             // [128][64]
    __hip_bfloat16* Bsub = (__hip_bfloat16*)(u_lds + 16384);   // [128][64]
    char* simt = u_lds;  // dword idx d at row r -> byte r*256 + ((d>>2)^(r&15))*16 + (d&3)*4

    const int tid  = threadIdx.x;
    const int lane = tid & 63;
    const int w    = tid >> 6;   // 0..7
    const int wr   = w >> 2;     // 0..1  (M direction, 64 rows each)
    const int wc   = w & 3;      // 0..3  (N direction, 32 cols each)
    const int i0   = blockIdx.y * 512;
    const int j0   = blockIdx.x * 512;

    // col-scan address offsets (16 per thread), hoisted out of all loops
    int coff[16];
    if (tid >= 128 && tid < 256) {
        const int cloc = tid - 128;
        const int cwc  = cloc >> 5;
        const int d    = cwc * 16 + (cloc & 15);       // dword index in row
        const int ul   = d >> 2;
        const int off  = (d & 3) * 4;
        #pragma unroll
        for (int j = 0; j < 16; ++j)
            coff[j] = j * 256 + ((ul ^ j) << 4) + off;
    }

    for (int q = tid; q < 512 * 10; q += 512) {
        (&rowlist[0][0])[q] = -1e30f;
        (&collist[0][0])[q] = -1e30f;
    }
    __syncthreads();

    for (int ti = 0; ti < 4; ++ti) {
        for (int tj = 0; tj < 4; ++tj) {
            f4v acc[4][2];
            #pragma unroll
            for (int m = 0; m < 4; ++m)
                #pragma unroll
                for (int n = 0; n < 2; ++n)
                    acc[m][n] = (f4v){0.f, 0.f, 0.f, 0.f};

            const __hip_bfloat16* Ab = A  + (size_t)(i0 + ti * 128) * DP;
            const __hip_bfloat16* Bb = Bm + (size_t)(j0 + tj * 128) * DP;

            for (int kb = 0; kb < 5; ++kb) {
                __syncthreads();   // prior phase (frag reads / scan) done
                // stage: 32 chunks of 1KB (16 A + 16 B), 4 per wave.
                // linear LDS dest; source col pre-swizzled: unit = u ^ (row&7)
                #pragma unroll
                for (int cc = 0; cc < 4; ++cc) {
                    const int c  = (w << 2) + cc;      // 0..31, wave-uniform
                    const int cm = c & 15;
                    const int rl = (cm << 3) + (lane >> 3);
                    const int ul = (lane & 7) ^ (lane >> 3);
                    if (c < 16)
                        gload_lds16(Ab + (size_t)rl * DP + kb * 64 + ul * 8,
                                    u_lds + cm * 1024);
                    else
                        gload_lds16(Bb + (size_t)rl * DP + kb * 64 + ul * 8,
                                    u_lds + 16384 + cm * 1024);
                }
                __syncthreads();   // drains vmcnt: staged data visible
                #pragma unroll
                for (int ks = 0; ks < 2; ++ks) {
                    s8v af[4], bfv[2];
                    const int ulog = ks * 4 + (lane >> 4);
                    const int up   = ulog ^ (lane & 7);   // row&7 == lane&7
                    #pragma unroll
                    for (int m = 0; m < 4; ++m) {
                        const int row = wr * 64 + m * 16 + (lane & 15);
                        af[m] = *reinterpret_cast<const s8v*>(Asub + row * 64 + up * 8);
                    }
                    #pragma unroll
                    for (int n = 0; n < 2; ++n) {
                        const int row = wc * 32 + n * 16 + (lane & 15);
                        bfv[n] = *reinterpret_cast<const s8v*>(Bsub + row * 64 + up * 8);
                    }
                    #pragma unroll
                    for (int m = 0; m < 4; ++m)
                        #pragma unroll
                        for (int n = 0; n < 2; ++n)
                            acc[m][n] = __builtin_amdgcn_mfma_f32_16x16x32_bf16(
                                af[m], bfv[n], acc[m][n], 0, 0, 0);
                }
            }
            __syncthreads();   // all frag reads done before simt overwrites staging

            // scatter acc -> packed bf16 dwords (lo = n0, hi = n1), swizzled
            // C/D layout: col = lane&15, row = (lane>>4)*4 + reg
            {
                const int d_idx = wc * 16 + (lane & 15);
                const int ul    = d_idx >> 2;
                const int boff  = (d_idx & 3) * 4;
                #pragma unroll
                for (int m = 0; m < 4; ++m) {
                    #pragma unroll
                    for (int r = 0; r < 4; ++r) {
                        const int rr = wr * 64 + m * 16 + (lane >> 4) * 4 + r;
                        __hip_bfloat16 b0 = __float2bfloat16(acc[m][0][r]);
                        __hip_bfloat16 b1 = __float2bfloat16(acc[m][1][r]);
                        unsigned u0 = *reinterpret_cast<unsigned short*>(&b0);
                        unsigned u1 = *reinterpret_cast<unsigned short*>(&b1);
                        *reinterpret_cast<unsigned*>(
                            simt + rr * 256 + ((ul ^ (rr & 15)) << 4) + boff)
                            = u0 | (u1 << 16);
                    }
                }
            }
            __syncthreads();

            // scans with group-max filtering
            if (tid < 128) {
                const int rloc = tid;
                const char* rbase = simt + rloc * 256;
                const int sw = rloc & 15;
                float* gl = rowlist[ti * 128 + rloc];
                float lst[10];
                #pragma unroll
                for (int q = 0; q < 10; ++q) lst[q] = gl[q];
                #pragma unroll
                for (int ub = 0; ub < 16; ++ub) {
                    uint4 dq = *reinterpret_cast<const uint4*>(rbase + ((ub ^ sw) << 4));
                    float v0 = hi_bf(dq.x), v1 = lo_bf(dq.x);
                    float v2 = hi_bf(dq.y), v3 = lo_bf(dq.y);
                    float v4 = hi_bf(dq.z), v5 = lo_bf(dq.z);
                    float v6 = hi_bf(dq.w), v7 = lo_bf(dq.w);
                    float gm = fmaxf(fmaxf(fmaxf(v0, v1), fmaxf(v2, v3)),
                                     fmaxf(fmaxf(v4, v5), fmaxf(v6, v7)));
                    if (gm > lst[9]) {
                        topk_insert(lst, v0); topk_insert(lst, v1);
                        topk_insert(lst, v2); topk_insert(lst, v3);
                        topk_insert(lst, v4); topk_insert(lst, v5);
                        topk_insert(lst, v6); topk_insert(lst, v7);
                    }
                }
                #pragma unroll
                for (int q = 0; q < 10; ++q) gl[q] = lst[q];
            } else if (tid < 256) {
                const int cloc = tid - 128;
                const int sh   = ((cloc & 31) >> 4) ? 0 : 16;  // hi half: no shift
                float* gl = collist[tj * 128 + cloc];
                float lst[10];
                #pragma unroll
                for (int q = 0; q < 10; ++q) lst[q] = gl[q];
                #pragma unroll
                for (int rb = 0; rb < 128; rb += 16) {
                    unsigned dv[16];
                    #pragma unroll
                    for (int j = 0; j < 16; ++j)
                        dv[j] = *reinterpret_cast<const unsigned*>(simt + rb * 256 + coff[j]);
                    float v[16];
                    #pragma unroll
                    for (int j = 0; j < 16; ++j)
                        v[j] = __uint_as_float((dv[j] << sh) & 0xFFFF0000u);
                    float g0 = fmaxf(fmaxf(fmaxf(v[0], v[1]), fmaxf(v[2], v[3])),
                                     fmaxf(fmaxf(v[4], v[5]), fmaxf(v[6], v[7])));
                    float g1 = fmaxf(fmaxf(fmaxf(v[8], v[9]), fmaxf(v[10], v[11])),
                                     fmaxf(fmaxf(v[12], v[13]), fmaxf(v[14], v[15])));
                    if (g0 > lst[9]) {
                        #pragma unroll
                        for (int j = 0; j < 8; ++j) topk_insert(lst, v[j]);
                    }
                    if (g1 > lst[9]) {
                        #pragma unroll
                        for (int j = 8; j < 16; ++j) topk_insert(lst, v[j]);
                    }
                }
                #pragma unroll
                for (int q = 0; q < 10; ++q) gl[q] = lst[q];
            }
            __syncthreads();
        }
    }

    // flush candidates
    for (int q = tid; q < 512 * 10; q += 512) {
        int rloc = q / 10, qq = q % 10;
        rowcand[((size_t)(i0 + rloc) * NCH + blockIdx.x) * 10 + qq] = rowlist[rloc][qq];
        colcand[((size_t)(j0 + rloc) * NCH + blockIdx.y) * 10 + qq] = collist[rloc][qq];
    }
}

// ---------------------------------------------------------------------------
// Kernel 3: merge 32 chunks x 10 candidates -> mean(top10) = rt / rs
// ---------------------------------------------------------------------------
__global__ __launch_bounds__(256) void reduce_topk(
        const float* __restrict__ rowcand, const float* __restrict__ colcand,
        float* __restrict__ rt, float* __restrict__ rs) {
    const int t = blockIdx.x * 256 + threadIdx.x;   // 0 .. 2N-1
    const bool isRow = (t < NN);
    const int  row   = isRow ? t : t - NN;
    const float* src = isRow ? rowcand : colcand;

    float lst[10];
    #pragma unroll
    for (int q = 0; q < 10; ++q) lst[q] = -1e30f;

    const float4* p = reinterpret_cast<const float4*>(src + (size_t)row * (NCH * 10));
    for (int c = 0; c < NCH * 10 / 4; ++c) {
        float4 v = p[c];
        float gm = fmaxf(fmaxf(v.x, v.y), fmaxf(v.z, v.w));
        if (gm > lst[9]) {
            topk_insert(lst, v.x); topk_insert(lst, v.y);
            topk_insert(lst, v.z); topk_insert(lst, v.w);
        }
    }
    float s = 0.f;
    #pragma unroll
    for (int q = 0; q < 10; ++q) s += lst[q];
    s *= 0.1f;
    if (isRow) rt[row] = s; else rs[row] = s;
}

// ---------------------------------------------------------------------------
// Kernel 4: gathered dots + CSLS logits.
// ---------------------------------------------------------------------------
__global__ __launch_bounds__(256) void logits_kernel(
        const __hip_bfloat16* __restrict__ srcH, const __hip_bfloat16* __restrict__ tgtH,
        const int* __restrict__ sidx, const int* __restrict__ tidx,
        const float* __restrict__ rt, const float* __restrict__ rs,
        float* __restrict__ out) {
    const int b    = blockIdx.x;
    const int lane = threadIdx.x & 63;
    const int w    = threadIdx.x >> 6;

    const int s0 = sidx[b * KK];
    const int t0 = tidx[b * KK];
    float ps[5], pt[5];
    #pragma unroll
    for (int j = 0; j < 5; ++j) {
        int d = lane + 64 * j;
        ps[j] = __bfloat162float(srcH[(size_t)s0 * DP + d]);
        pt[j] = __bfloat162float(tgtH[(size_t)t0 * DP + d]);
    }
    const float rt_s0 = rt[s0];
    const float rs_t0 = rs[t0];

    for (int kk = w; kk < KK; kk += 4) {
        const int it = tidx[b * KK + kk];
        const int is = sidx[b * KK + kk];
        float a = 0.f, c = 0.f;
        #pragma unroll
        for (int j = 0; j < 5; ++j) {
            int d = lane + 64 * j;
            a += ps[j] * __bfloat162float(tgtH[(size_t)it * DP + d]);
            c += pt[j] * __bfloat162float(srcH[(size_t)is * DP + d]);
        }
        #pragma unroll
        for (int o = 32; o; o >>= 1) {
            a += __shfl_xor(a, o);
            c += __shfl_xor(c, o);
        }
        if (lane == 0) {
            out[b * KK + kk]           = 2.f * a - rt_s0 - rs[it];
            out[BB * KK + b * KK + kk] = 2.f * c - rs_t0 - rt[is];
        }
    }
}

// ---------------------------------------------------------------------------
extern "C" void kernel_launch(void* const* d_in, const int* in_sizes, int n_in,
                              void* d_out, int out_size, void* d_ws, size_t ws_size,
                              hipStream_t stream) {
    const float* nf_src = (const float*)d_in[0];
    const float* nf_tgt = (const float*)d_in[1];
    const int*   sidx   = (const int*)d_in[2];
    const int*   tidx   = (const int*)d_in[3];
    const float* svs    = (const float*)d_in[4];
    const float* tvs    = (const float*)d_in[5];

    char* ws = (char*)d_ws;
    const size_t SZ_H    = (size_t)NN * DP * 2;            // bf16 features
    const size_t SZ_CAND = (size_t)NN * NCH * 10 * 4;
    __hip_bfloat16* srcH = (__hip_bfloat16*)ws;
    __hip_bfloat16* tgtH = (__hip_bfloat16*)(ws + SZ_H);
    float* rowcand = (float*)(ws + 2 * SZ_H);
    float* colcand = (float*)(ws + 2 * SZ_H + SZ_CAND);
    float* rt      = (float*)(ws + 2 * SZ_H + 2 * SZ_CAND);
    float* rs      = (float*)(ws + 2 * SZ_H + 2 * SZ_CAND + (size_t)NN * 4);

    tower_kernel<<<NN / 4, 256, 0, stream>>>(nf_src, svs, srcH);
    tower_kernel<<<NN / 4, 256, 0, stream>>>(nf_tgt, tvs, tgtH);
    sim_topk_kernel<<<dim3(NCH, NCH), 512, 0, stream>>>(srcH, tgtH, rowcand, colcand);
    reduce_topk<<<(2 * NN) / 256, 256, 0, stream>>>(rowcand, colcand, rt, rs);
    logits_kernel<<<BB, 256, 0, stream>>>(srcH, tgtH, sidx, tidx, rt, rs, (float*)d_out);
}

// Round 4
// 801.997 us; speedup vs baseline: 1.2422x; 1.2422x over previous
//
#include <hip/hip_runtime.h>
#include <hip/hip_bf16.h>

#define NN 16384
#define DD 300
#define DP 320
#define RR 10
#define BB 1024
#define KK 64
#define NCH 32   // column/row chunks (N / 512)

typedef __attribute__((ext_vector_type(8))) short s8v;   // 8 bf16 (4 VGPRs)
typedef __attribute__((ext_vector_type(4))) float f4v;   // MFMA accumulator

// ---- monotone bf16->u16 key (order-preserving, packed 2 per dword) --------
__device__ __forceinline__ unsigned mono2(unsigned d) {
    // per u16 half: pos -> b|0x8000 ; neg -> ~b   (strictly increasing map)
    unsigned s = ((d >> 15) & 0x10001u) * 0xFFFFu;
    return d ^ (s | 0x80008000u);
}
__device__ __forceinline__ unsigned pack_mono(float a, float b) {
    __hip_bfloat16 ba = __float2bfloat16(a);
    __hip_bfloat16 bb = __float2bfloat16(b);
    unsigned ua = *reinterpret_cast<unsigned short*>(&ba);
    unsigned ub = *reinterpret_cast<unsigned short*>(&bb);
    return mono2(ua | (ub << 16));
}
__device__ __forceinline__ float key2f(unsigned k) {
    unsigned k16 = k >> 16;
    unsigned b = (k16 & 0x8000u) ? (k16 ^ 0x8000u) : (~k16 & 0xFFFFu);
    return __uint_as_float(b << 16);
}

// sorted-descending top-10 insert, unsigned keys (max/min chain)
__device__ __forceinline__ void ins10(unsigned (&lst)[10], unsigned v) {
    #pragma unroll
    for (int q = 0; q < 10; ++q) {
        unsigned a  = lst[q];
        unsigned mx = a > v ? a : v;
        v           = a > v ? v : a;
        lst[q] = mx;
    }
}

// extract-max loop over an 8-value group: wave-cheap divergence
__device__ __forceinline__ void scan8(unsigned (&v)[8], unsigned (&lst)[10]) {
    unsigned g = v[0];
    #pragma unroll
    for (int j = 1; j < 8; ++j) g = g > v[j] ? g : v[j];
    while (__any((int)(g > lst[9]))) {
        const bool mine = g > lst[9];
        if (mine) ins10(lst, g);
        const unsigned s = mine ? g : 0u;
        unsigned ng = 0u;
        #pragma unroll
        for (int j = 0; j < 8; ++j) {
            v[j] = (v[j] == s) ? 0u : v[j];
            ng = ng > v[j] ? ng : v[j];
        }
        g = ng;
    }
}

// ---------------------------------------------------------------------------
// Kernel 1: Householder tower + L2 normalize + bf16 cast (padded to 320).
// ---------------------------------------------------------------------------
__global__ __launch_bounds__(256) void tower_kernel(
        const float* __restrict__ feat, const float* __restrict__ vs,
        __hip_bfloat16* __restrict__ out) {
    __shared__ float vsh[RR * DD];
    const int tid = threadIdx.x;
    for (int i = tid; i < RR * DD; i += 256) vsh[i] = vs[i];
    __syncthreads();

    const int lane = tid & 63;
    const int wave = tid >> 6;
    const int row  = blockIdx.x * 4 + wave;

    float h[5];
    #pragma unroll
    for (int j = 0; j < 5; ++j) {
        int d = lane + 64 * j;
        h[j] = (d < DD) ? feat[(size_t)row * DD + d] : 0.f;
    }

    #pragma unroll
    for (int r = 0; r < RR; ++r) {
        float vl[5];
        float hv = 0.f, vv = 0.f;
        #pragma unroll
        for (int j = 0; j < 5; ++j) {
            int d = lane + 64 * j;
            float v = (d < DD) ? vsh[r * DD + d] : 0.f;
            vl[j] = v;
            hv += h[j] * v;
            vv += v * v;
        }
        #pragma unroll
        for (int o = 32; o; o >>= 1) {
            hv += __shfl_xor(hv, o);
            vv += __shfl_xor(vv, o);
        }
        float coef = hv / vv;
        #pragma unroll
        for (int j = 0; j < 5; ++j) h[j] -= coef * vl[j];
    }

    float nn = 0.f;
    #pragma unroll
    for (int j = 0; j < 5; ++j) nn += h[j] * h[j];
    #pragma unroll
    for (int o = 32; o; o >>= 1) nn += __shfl_xor(nn, o);
    float scale = 1.f / fmaxf(sqrtf(nn), 1e-12f);

    #pragma unroll
    for (int j = 0; j < 5; ++j) {
        int d = lane + 64 * j;
        float val = (d < DD) ? h[j] * scale : 0.f;
        out[(size_t)row * DP + d] = __float2bfloat16(val);
    }
}

// ---------------------------------------------------------------------------
// Kernel 2: 512x512 sim region per block (grid 32x32), 16 inner 128x128 MFMA
// tiles. Reg-staged LDS (swizzled writes), monotone-key sim tile, colmax
// side-tile, extract-max top-k scans. LDS ~62KB -> 2 blocks/CU.
// ---------------------------------------------------------------------------
__global__ __launch_bounds__(512, 4) void sim_topk_kernel(
        const __hip_bfloat16* __restrict__ A,   // src_hn [N][320]
        const __hip_bfloat16* __restrict__ Bm,  // tgt_hn [N][320]
        unsigned* __restrict__ rowcand,         // [N][NCH][10] (u32 keys)
        unsigned* __restrict__ colcand) {       // [N][NCH][10] (u32 keys)
    // union: staging (Asub|Bsub [128][64] bf16, unit-swizzled) = 32768 B
    //      | simt (key-dword [128][64], unit-XOR-swizzled)
    __shared__ __align__(16) char u_lds[32768];
    __shared__ unsigned colmax[32 * 64];        // [rowgroup g][dword dw] keys
    __shared__ unsigned collist[512][11];       // padded stride 11

    __hip_bfloat16* Asub = (__hip_bfloat16*)u_lds;             // [128][64]
    __hip_bfloat16* Bsub = (__hip_bfloat16*)(u_lds + 16384);   // [128][64]
    char* simt = u_lds;  // dword idx d at row r -> byte r*256 + ((d>>2 ^ (r&15))<<4) + (d&3)*4

    const int tid  = threadIdx.x;
    const int lane = tid & 63;
    const int w    = tid >> 6;   // 0..7
    const int wr   = w >> 2;     // 0..1
    const int wc   = w & 3;      // 0..3
    const int i0   = blockIdx.y * 512;
    const int j0   = blockIdx.x * 512;

    unsigned rlst[10];
    #pragma unroll
    for (int q = 0; q < 10; ++q) rlst[q] = 0u;

    for (int q = tid; q < 512 * 11; q += 512) (&collist[0][0])[q] = 0u;
    __syncthreads();

    for (int ti = 0; ti < 4; ++ti) {
        for (int tj = 0; tj < 4; ++tj) {
            f4v acc[4][2];
            #pragma unroll
            for (int m = 0; m < 4; ++m)
                #pragma unroll
                for (int n = 0; n < 2; ++n)
                    acc[m][n] = (f4v){0.f, 0.f, 0.f, 0.f};

            const __hip_bfloat16* Ab = A  + (size_t)(i0 + ti * 128) * DP;
            const __hip_bfloat16* Bb = Bm + (size_t)(j0 + tj * 128) * DP;

            for (int kb = 0; kb < 5; ++kb) {
                __syncthreads();
                {   // reg-staged: linear global reads, swizzled LDS writes
                    const int r0 = tid >> 3, u0 = tid & 7;
                    const size_t go = (size_t)r0 * DP + kb * 64 + u0 * 8;
                    int4 va0 = *reinterpret_cast<const int4*>(Ab + go);
                    int4 vb0 = *reinterpret_cast<const int4*>(Bb + go);
                    int4 va1 = *reinterpret_cast<const int4*>(Ab + go + (size_t)64 * DP);
                    int4 vb1 = *reinterpret_cast<const int4*>(Bb + go + (size_t)64 * DP);
                    const int p0 = (u0 ^ (r0 & 7)) * 8;   // (r0+64)&7 == r0&7
                    *reinterpret_cast<int4*>(Asub + r0 * 64 + p0)        = va0;
                    *reinterpret_cast<int4*>(Bsub + r0 * 64 + p0)        = vb0;
                    *reinterpret_cast<int4*>(Asub + (r0 + 64) * 64 + p0) = va1;
                    *reinterpret_cast<int4*>(Bsub + (r0 + 64) * 64 + p0) = vb1;
                }
                __syncthreads();
                #pragma unroll
                for (int ks = 0; ks < 2; ++ks) {
                    s8v af[4], bfv[2];
                    const int ulog = ks * 4 + (lane >> 4);
                    const int up   = ulog ^ (lane & 7);   // row&7 == lane&7
                    #pragma unroll
                    for (int m = 0; m < 4; ++m) {
                        const int row = wr * 64 + m * 16 + (lane & 15);
                        af[m] = *reinterpret_cast<const s8v*>(Asub + row * 64 + up * 8);
                    }
                    #pragma unroll
                    for (int n = 0; n < 2; ++n) {
                        const int row = wc * 32 + n * 16 + (lane & 15);
                        bfv[n] = *reinterpret_cast<const s8v*>(Bsub + row * 64 + up * 8);
                    }
                    #pragma unroll
                    for (int m = 0; m < 4; ++m)
                        #pragma unroll
                        for (int n = 0; n < 2; ++n)
                            acc[m][n] = __builtin_amdgcn_mfma_f32_16x16x32_bf16(
                                af[m], bfv[n], acc[m][n], 0, 0, 0);
                }
            }
            __syncthreads();   // frag reads done before simt overwrites staging

            // scatter -> monotone-key dwords (lo = col, hi = col+16) + colmax
            // C/D layout: col = lane&15, row = (lane>>4)*4 + reg
            {
                const int d_idx = wc * 16 + (lane & 15);
                const int ul    = d_idx >> 2;
                const int bo    = (d_idx & 3) * 4;
                #pragma unroll
                for (int m = 0; m < 4; ++m) {
                    #pragma unroll
                    for (int r = 0; r < 4; ++r) {
                        const int rr = wr * 64 + m * 16 + (lane >> 4) * 4 + r;
                        unsigned d = pack_mono(acc[m][0][r], acc[m][1][r]);
                        *reinterpret_cast<unsigned*>(
                            simt + rr * 256 + ((ul ^ (rr & 15)) << 4) + bo) = d;
                    }
                    float m0 = fmaxf(fmaxf(acc[m][0][0], acc[m][0][1]),
                                     fmaxf(acc[m][0][2], acc[m][0][3]));
                    float m1 = fmaxf(fmaxf(acc[m][1][0], acc[m][1][1]),
                                     fmaxf(acc[m][1][2], acc[m][1][3]));
                    const int g = wr * 16 + m * 4 + (lane >> 4);
                    colmax[g * 64 + d_idx] = pack_mono(m0, m1);
                }
            }
            __syncthreads();

            if (tid < 256) {
                // row scan: 2 threads/row, 8 key-dword-units each
                const int rloc = tid >> 1;
                const char* rbase = simt + rloc * 256;
                const int sw  = rloc & 15;
                const int ub0 = (tid & 1) * 8;
                #pragma unroll
                for (int ub = 0; ub < 8; ++ub) {
                    uint4 q = *reinterpret_cast<const uint4*>(
                        rbase + (((ub0 + ub) ^ sw) << 4));
                    unsigned v[8];
                    v[0] = (q.x << 16) | 0u; v[1] = (q.x & 0xFFFF0000u) | 1u;
                    v[2] = (q.y << 16) | 2u; v[3] = (q.y & 0xFFFF0000u) | 3u;
                    v[4] = (q.z << 16) | 4u; v[5] = (q.z & 0xFFFF0000u) | 5u;
                    v[6] = (q.w << 16) | 6u; v[7] = (q.w & 0xFFFF0000u) | 7u;
                    scan8(v, rlst);
                }
            } else if (tid < 384) {
                // col scan: 1 thread/col over colmax rowgroups + drill
                const int c   = tid - 256;
                const int dw  = (c >> 5) * 16 + (c & 15);
                const int hi  = (c >> 4) & 1;
                const int ulc = dw >> 2;
                const int boc = (dw & 3) * 4;
                unsigned* cl = collist[tj * 128 + c];
                unsigned clst[10];
                #pragma unroll
                for (int q = 0; q < 10; ++q) clst[q] = cl[q];
                #pragma unroll
                for (int gb = 0; gb < 4; ++gb) {
                    unsigned v[8];
                    #pragma unroll
                    for (int j = 0; j < 8; ++j) {
                        unsigned d = colmax[(gb * 8 + j) * 64 + dw];
                        unsigned k16 = hi ? (d >> 16) : (d & 0xFFFFu);
                        v[j] = (k16 << 16) | (unsigned)(gb * 8 + j);
                    }
                    unsigned g = v[0];
                    #pragma unroll
                    for (int j = 1; j < 8; ++j) g = g > v[j] ? g : v[j];
                    while (__any((int)(g > clst[9]))) {
                        const bool mine = g > clst[9];
                        if (mine) {
                            const int G = (int)(g & 31u);
                            #pragma unroll
                            for (int r4 = 0; r4 < 4; ++r4) {
                                const int row = G * 4 + r4;
                                unsigned d = *reinterpret_cast<const unsigned*>(
                                    simt + row * 256 + ((ulc ^ (row & 15)) << 4) + boc);
                                unsigned k = hi ? (d & 0xFFFF0000u) : (d << 16);
                                if (k > clst[9]) ins10(clst, k);
                            }
                        }
                        const unsigned s = mine ? g : 0u;
                        unsigned ng = 0u;
                        #pragma unroll
                        for (int j = 0; j < 8; ++j) {
                            v[j] = (v[j] == s) ? 0u : v[j];
                            ng = ng > v[j] ? ng : v[j];
                        }
                        g = ng;
                    }
                }
                #pragma unroll
                for (int q = 0; q < 10; ++q) cl[q] = clst[q];
            }
            __syncthreads();
        }

        // flush row lists for this ti band (pair-merge via shuffle)
        if (tid < 256) {
            unsigned merged[10];
            #pragma unroll
            for (int q = 0; q < 10; ++q) merged[q] = rlst[q];
            #pragma unroll
            for (int q = 0; q < 10; ++q) {
                unsigned o = (unsigned)__shfl_xor((int)rlst[q], 1);
                if (o > merged[9]) ins10(merged, o);
            }
            if (!(tid & 1)) {
                unsigned* dst = rowcand +
                    ((size_t)(i0 + ti * 128 + (tid >> 1)) * NCH + blockIdx.x) * 10;
                #pragma unroll
                for (int q = 0; q < 10; ++q) dst[q] = merged[q];
            }
            #pragma unroll
            for (int q = 0; q < 10; ++q) rlst[q] = 0u;
        }
    }

    // flush col lists
    __syncthreads();
    for (int q = tid; q < 512 * 10; q += 512) {
        int cl = q / 10, qq = q % 10;
        colcand[((size_t)(j0 + cl) * NCH + blockIdx.y) * 10 + qq] = collist[cl][qq];
    }
}

// ---------------------------------------------------------------------------
// Kernel 3: merge 32 chunks x 10 key-candidates -> mean(top10) = rt / rs
// ---------------------------------------------------------------------------
__global__ __launch_bounds__(256) void reduce_topk(
        const unsigned* __restrict__ rowcand, const unsigned* __restrict__ colcand,
        float* __restrict__ rt, float* __restrict__ rs) {
    const int t = blockIdx.x * 256 + threadIdx.x;   // 0 .. 2N-1
    const bool isRow = (t < NN);
    const int  row   = isRow ? t : t - NN;
    const unsigned* src = isRow ? rowcand : colcand;

    unsigned lst[10];
    #pragma unroll
    for (int q = 0; q < 10; ++q) lst[q] = 0u;

    const uint4* p = reinterpret_cast<const uint4*>(src + (size_t)row * (NCH * 10));
    for (int c = 0; c < NCH * 10 / 4; ++c) {
        uint4 v = p[c];
        unsigned g01 = v.x > v.y ? v.x : v.y;
        unsigned g23 = v.z > v.w ? v.z : v.w;
        unsigned gm  = g01 > g23 ? g01 : g23;
        if (gm > lst[9]) {
            if (v.x > lst[9]) ins10(lst, v.x);
            if (v.y > lst[9]) ins10(lst, v.y);
            if (v.z > lst[9]) ins10(lst, v.z);
            if (v.w > lst[9]) ins10(lst, v.w);
        }
    }
    float s = 0.f;
    #pragma unroll
    for (int q = 0; q < 10; ++q) s += key2f(lst[q]);
    s *= 0.1f;
    if (isRow) rt[row] = s; else rs[row] = s;
}

// ---------------------------------------------------------------------------
// Kernel 4: gathered dots + CSLS logits.
// ---------------------------------------------------------------------------
__global__ __launch_bounds__(256) void logits_kernel(
        const __hip_bfloat16* __restrict__ srcH, const __hip_bfloat16* __restrict__ tgtH,
        const int* __restrict__ sidx, const int* __restrict__ tidx,
        const float* __restrict__ rt, const float* __restrict__ rs,
        float* __restrict__ out) {
    const int b    = blockIdx.x;
    const int lane = threadIdx.x & 63;
    const int w    = threadIdx.x >> 6;

    const int s0 = sidx[b * KK];
    const int t0 = tidx[b * KK];
    float ps[5], pt[5];
    #pragma unroll
    for (int j = 0; j < 5; ++j) {
        int d = lane + 64 * j;
        ps[j] = __bfloat162float(srcH[(size_t)s0 * DP + d]);
        pt[j] = __bfloat162float(tgtH[(size_t)t0 * DP + d]);
    }
    const float rt_s0 = rt[s0];
    const float rs_t0 = rs[t0];

    for (int kk = w; kk < KK; kk += 4) {
        const int it = tidx[b * KK + kk];
        const int is = sidx[b * KK + kk];
        float a = 0.f, c = 0.f;
        #pragma unroll
        for (int j = 0; j < 5; ++j) {
            int d = lane + 64 * j;
            a += ps[j] * __bfloat162float(tgtH[(size_t)it * DP + d]);
            c += pt[j] * __bfloat162float(srcH[(size_t)is * DP + d]);
        }
        #pragma unroll
        for (int o = 32; o; o >>= 1) {
            a += __shfl_xor(a, o);
            c += __shfl_xor(c, o);
        }
        if (lane == 0) {
            out[b * KK + kk]           = 2.f * a - rt_s0 - rs[it];
            out[BB * KK + b * KK + kk] = 2.f * c - rs_t0 - rt[is];
        }
    }
}

// ---------------------------------------------------------------------------
extern "C" void kernel_launch(void* const* d_in, const int* in_sizes, int n_in,
                              void* d_out, int out_size, void* d_ws, size_t ws_size,
                              hipStream_t stream) {
    const float* nf_src = (const float*)d_in[0];
    const float* nf_tgt = (const float*)d_in[1];
    const int*   sidx   = (const int*)d_in[2];
    const int*   tidx   = (const int*)d_in[3];
    const float* svs    = (const float*)d_in[4];
    const float* tvs    = (const float*)d_in[5];

    char* ws = (char*)d_ws;
    const size_t SZ_H    = (size_t)NN * DP * 2;            // bf16 features
    const size_t SZ_CAND = (size_t)NN * NCH * 10 * 4;
    __hip_bfloat16* srcH = (__hip_bfloat16*)ws;
    __hip_bfloat16* tgtH = (__hip_bfloat16*)(ws + SZ_H);
    unsigned* rowcand = (unsigned*)(ws + 2 * SZ_H);
    unsigned* colcand = (unsigned*)(ws + 2 * SZ_H + SZ_CAND);
    float* rt = (float*)(ws + 2 * SZ_H + 2 * SZ_CAND);
    float* rs = (float*)(ws + 2 * SZ_H + 2 * SZ_CAND + (size_t)NN * 4);

    tower_kernel<<<NN / 4, 256, 0, stream>>>(nf_src, svs, srcH);
    tower_kernel<<<NN / 4, 256, 0, stream>>>(nf_tgt, tvs, tgtH);
    sim_topk_kernel<<<dim3(NCH, NCH), 512, 0, stream>>>(srcH, tgtH, rowcand, colcand);
    reduce_topk<<<(2 * NN) / 256, 256, 0, stream>>>(rowcand, colcand, rt, rs);
    logits_kernel<<<BB, 256, 0, stream>>>(srcH, tgtH, sidx, tidx, rt, rs, (float*)d_out);
}

// Round 5
// 801.063 us; speedup vs baseline: 1.2437x; 1.0012x over previous
//
#include <hip/hip_runtime.h>
#include <hip/hip_bf16.h>

#define NN 16384
#define DD 300
#define DP 320
#define RR 10
#define BB 1024
#define KK 64
#define NCH 32   // column/row chunks (N / 512)

typedef __attribute__((ext_vector_type(8))) short s8v;   // 8 bf16 (4 VGPRs)
typedef __attribute__((ext_vector_type(4))) float f4v;   // MFMA accumulator

// ---- monotone bf16->u16 key (order-preserving, packed 2 per dword) --------
__device__ __forceinline__ unsigned mono2(unsigned d) {
    // per u16 half: pos -> b|0x8000 ; neg -> ~b   (strictly increasing map)
    unsigned s = ((d >> 15) & 0x10001u) * 0xFFFFu;
    return d ^ (s | 0x80008000u);
}
__device__ __forceinline__ unsigned pack_mono(float a, float b) {
    __hip_bfloat16 ba = __float2bfloat16(a);
    __hip_bfloat16 bb = __float2bfloat16(b);
    unsigned ua = *reinterpret_cast<unsigned short*>(&ba);
    unsigned ub = *reinterpret_cast<unsigned short*>(&bb);
    return mono2(ua | (ub << 16));
}
__device__ __forceinline__ float key2f(unsigned k) {
    unsigned k16 = k >> 16;
    unsigned b = (k16 & 0x8000u) ? (k16 ^ 0x8000u) : (~k16 & 0xFFFFu);
    return __uint_as_float(b << 16);
}

// sorted-descending top-10 insert, unsigned keys (max/min chain)
__device__ __forceinline__ void ins10(unsigned (&lst)[10], unsigned v) {
    #pragma unroll
    for (int q = 0; q < 10; ++q) {
        unsigned a  = lst[q];
        unsigned mx = a > v ? a : v;
        v           = a > v ? v : a;
        lst[q] = mx;
    }
}

// extract-max loop over an 8-value group: wave-cheap divergence
__device__ __forceinline__ void scan8(unsigned (&v)[8], unsigned (&lst)[10]) {
    unsigned g = v[0];
    #pragma unroll
    for (int j = 1; j < 8; ++j) g = g > v[j] ? g : v[j];
    while (__any((int)(g > lst[9]))) {
        const bool mine = g > lst[9];
        if (mine) ins10(lst, g);
        const unsigned s = mine ? g : 0u;
        unsigned ng = 0u;
        #pragma unroll
        for (int j = 0; j < 8; ++j) {
            v[j] = (v[j] == s) ? 0u : v[j];
            ng = ng > v[j] ? ng : v[j];
        }
        g = ng;
    }
}

// ---------------------------------------------------------------------------
// Kernel 1: Householder tower + L2 normalize + bf16 cast (padded to 320).
// ---------------------------------------------------------------------------
__global__ __launch_bounds__(256) void tower_kernel(
        const float* __restrict__ feat, const float* __restrict__ vs,
        __hip_bfloat16* __restrict__ out) {
    __shared__ float vsh[RR * DD];
    const int tid = threadIdx.x;
    for (int i = tid; i < RR * DD; i += 256) vsh[i] = vs[i];
    __syncthreads();

    const int lane = tid & 63;
    const int wave = tid >> 6;
    const int row  = blockIdx.x * 4 + wave;

    float h[5];
    #pragma unroll
    for (int j = 0; j < 5; ++j) {
        int d = lane + 64 * j;
        h[j] = (d < DD) ? feat[(size_t)row * DD + d] : 0.f;
    }

    #pragma unroll
    for (int r = 0; r < RR; ++r) {
        float vl[5];
        float hv = 0.f, vv = 0.f;
        #pragma unroll
        for (int j = 0; j < 5; ++j) {
            int d = lane + 64 * j;
            float v = (d < DD) ? vsh[r * DD + d] : 0.f;
            vl[j] = v;
            hv += h[j] * v;
            vv += v * v;
        }
        #pragma unroll
        for (int o = 32; o; o >>= 1) {
            hv += __shfl_xor(hv, o);
            vv += __shfl_xor(vv, o);
        }
        float coef = hv / vv;
        #pragma unroll
        for (int j = 0; j < 5; ++j) h[j] -= coef * vl[j];
    }

    float nn = 0.f;
    #pragma unroll
    for (int j = 0; j < 5; ++j) nn += h[j] * h[j];
    #pragma unroll
    for (int o = 32; o; o >>= 1) nn += __shfl_xor(nn, o);
    float scale = 1.f / fmaxf(sqrtf(nn), 1e-12f);

    #pragma unroll
    for (int j = 0; j < 5; ++j) {
        int d = lane + 64 * j;
        float val = (d < DD) ? h[j] * scale : 0.f;
        out[(size_t)row * DP + d] = __float2bfloat16(val);
    }
}

// ---------------------------------------------------------------------------
// Kernel 2: 512x512 sim region per block (grid 32x32), 16 inner 128x128 MFMA
// tiles. Reg-staged LDS (swizzled writes) with kb+1 prefetch (T14 split),
// monotone-key sim tile, colmax side-tile, extract-max top-k scans.
// LDS 62KB -> 2 blocks/CU; waves_per_eu(4) -> 128 VGPR cap (no spills).
// ---------------------------------------------------------------------------
__global__ __attribute__((amdgpu_waves_per_eu(4))) __launch_bounds__(512)
void sim_topk_kernel(
        const __hip_bfloat16* __restrict__ A,   // src_hn [N][320]
        const __hip_bfloat16* __restrict__ Bm,  // tgt_hn [N][320]
        unsigned* __restrict__ rowcand,         // [N][NCH][10] (u32 keys)
        unsigned* __restrict__ colcand) {       // [N][NCH][10] (u32 keys)
    // union: staging (Asub|Bsub [128][64] bf16, unit-swizzled) = 32768 B
    //      | simt (key-dword [128][64], unit-XOR-swizzled)
    __shared__ __align__(16) char u_lds[32768];
    __shared__ unsigned colmax[32 * 64];        // [rowgroup g][dword dw] keys
    __shared__ unsigned collist[512][11];       // padded stride 11

    __hip_bfloat16* Asub = (__hip_bfloat16*)u_lds;             // [128][64]
    __hip_bfloat16* Bsub = (__hip_bfloat16*)(u_lds + 16384);   // [128][64]
    char* simt = u_lds;  // dword idx d at row r -> byte r*256 + ((d>>2 ^ (r&15))<<4) + (d&3)*4

    const int tid  = threadIdx.x;
    const int lane = tid & 63;
    const int w    = tid >> 6;   // 0..7
    const int wr   = w >> 2;     // 0..1
    const int wc   = w & 3;      // 0..3
    const int i0   = blockIdx.y * 512;
    const int j0   = blockIdx.x * 512;

    unsigned rlst[10];
    #pragma unroll
    for (int q = 0; q < 10; ++q) rlst[q] = 0u;

    for (int q = tid; q < 512 * 11; q += 512) (&collist[0][0])[q] = 0u;
    __syncthreads();

    const int sr0 = tid >> 3, su0 = tid & 7;
    const int sp0 = (su0 ^ (sr0 & 7)) * 8;   // swizzled LDS unit offset

    for (int ti = 0; ti < 4; ++ti) {
        for (int tj = 0; tj < 4; ++tj) {
            f4v acc[4][2];
            #pragma unroll
            for (int m = 0; m < 4; ++m)
                #pragma unroll
                for (int n = 0; n < 2; ++n)
                    acc[m][n] = (f4v){0.f, 0.f, 0.f, 0.f};

            const __hip_bfloat16* Ab = A  + (size_t)(i0 + ti * 128) * DP;
            const __hip_bfloat16* Bb = Bm + (size_t)(j0 + tj * 128) * DP;

            // prologue: prefetch kb=0 into regs
            size_t go = (size_t)sr0 * DP + su0 * 8;
            int4 va0 = *reinterpret_cast<const int4*>(Ab + go);
            int4 vb0 = *reinterpret_cast<const int4*>(Bb + go);
            int4 va1 = *reinterpret_cast<const int4*>(Ab + go + (size_t)64 * DP);
            int4 vb1 = *reinterpret_cast<const int4*>(Bb + go + (size_t)64 * DP);

            #pragma unroll
            for (int kb = 0; kb < 5; ++kb) {
                __syncthreads();   // prior phase (frag reads / scan) done
                *reinterpret_cast<int4*>(Asub + sr0 * 64 + sp0)        = va0;
                *reinterpret_cast<int4*>(Bsub + sr0 * 64 + sp0)        = vb0;
                *reinterpret_cast<int4*>(Asub + (sr0 + 64) * 64 + sp0) = va1;
                *reinterpret_cast<int4*>(Bsub + (sr0 + 64) * 64 + sp0) = vb1;
                __syncthreads();
                if (kb < 4) {      // prefetch kb+1: latency hides under MFMA
                    go += 64;
                    va0 = *reinterpret_cast<const int4*>(Ab + go);
                    vb0 = *reinterpret_cast<const int4*>(Bb + go);
                    va1 = *reinterpret_cast<const int4*>(Ab + go + (size_t)64 * DP);
                    vb1 = *reinterpret_cast<const int4*>(Bb + go + (size_t)64 * DP);
                }
                #pragma unroll
                for (int ks = 0; ks < 2; ++ks) {
                    s8v af[4], bfv[2];
                    const int ulog = ks * 4 + (lane >> 4);
                    const int up   = ulog ^ (lane & 7);   // row&7 == lane&7
                    #pragma unroll
                    for (int m = 0; m < 4; ++m) {
                        const int row = wr * 64 + m * 16 + (lane & 15);
                        af[m] = *reinterpret_cast<const s8v*>(Asub + row * 64 + up * 8);
                    }
                    #pragma unroll
                    for (int n = 0; n < 2; ++n) {
                        const int row = wc * 32 + n * 16 + (lane & 15);
                        bfv[n] = *reinterpret_cast<const s8v*>(Bsub + row * 64 + up * 8);
                    }
                    #pragma unroll
                    for (int m = 0; m < 4; ++m)
                        #pragma unroll
                        for (int n = 0; n < 2; ++n)
                            acc[m][n] = __builtin_amdgcn_mfma_f32_16x16x32_bf16(
                                af[m], bfv[n], acc[m][n], 0, 0, 0);
                }
            }
            __syncthreads();   // frag reads done before simt overwrites staging

            // scatter -> monotone-key dwords (lo = col, hi = col+16) + colmax
            // C/D layout: col = lane&15, row = (lane>>4)*4 + reg
            {
                const int d_idx = wc * 16 + (lane & 15);
                const int ul    = d_idx >> 2;
                const int bo    = (d_idx & 3) * 4;
                #pragma unroll
                for (int m = 0; m < 4; ++m) {
                    #pragma unroll
                    for (int r = 0; r < 4; ++r) {
                        const int rr = wr * 64 + m * 16 + (lane >> 4) * 4 + r;
                        unsigned d = pack_mono(acc[m][0][r], acc[m][1][r]);
                        *reinterpret_cast<unsigned*>(
                            simt + rr * 256 + ((ul ^ (rr & 15)) << 4) + bo) = d;
                    }
                    float m0 = fmaxf(fmaxf(acc[m][0][0], acc[m][0][1]),
                                     fmaxf(acc[m][0][2], acc[m][0][3]));
                    float m1 = fmaxf(fmaxf(acc[m][1][0], acc[m][1][1]),
                                     fmaxf(acc[m][1][2], acc[m][1][3]));
                    const int g = wr * 16 + m * 4 + (lane >> 4);
                    colmax[g * 64 + d_idx] = pack_mono(m0, m1);
                }
            }
            __syncthreads();

            if (tid < 256) {
                // row scan: 2 threads/row, 8 key-dword-units each
                const int rloc = tid >> 1;
                const char* rbase = simt + rloc * 256;
                const int sw  = rloc & 15;
                const int ub0 = (tid & 1) * 8;
                #pragma unroll
                for (int ub = 0; ub < 8; ++ub) {
                    uint4 q = *reinterpret_cast<const uint4*>(
                        rbase + (((ub0 + ub) ^ sw) << 4));
                    unsigned v[8];
                    v[0] = (q.x << 16) | 0u; v[1] = (q.x & 0xFFFF0000u) | 1u;
                    v[2] = (q.y << 16) | 2u; v[3] = (q.y & 0xFFFF0000u) | 3u;
                    v[4] = (q.z << 16) | 4u; v[5] = (q.z & 0xFFFF0000u) | 5u;
                    v[6] = (q.w << 16) | 6u; v[7] = (q.w & 0xFFFF0000u) | 7u;
                    scan8(v, rlst);
                }
            } else if (tid < 384) {
                // col scan: 1 thread/col over colmax rowgroups + drill
                const int c   = tid - 256;
                const int dw  = (c >> 5) * 16 + (c & 15);
                const int hi  = (c >> 4) & 1;
                const int ulc = dw >> 2;
                const int boc = (dw & 3) * 4;
                unsigned* cl = collist[tj * 128 + c];
                unsigned clst[10];
                #pragma unroll
                for (int q = 0; q < 10; ++q) clst[q] = cl[q];
                #pragma unroll
                for (int gb = 0; gb < 4; ++gb) {
                    unsigned v[8];
                    #pragma unroll
                    for (int j = 0; j < 8; ++j) {
                        unsigned d = colmax[(gb * 8 + j) * 64 + dw];
                        unsigned k16 = hi ? (d >> 16) : (d & 0xFFFFu);
                        v[j] = (k16 << 16) | (unsigned)(gb * 8 + j);
                    }
                    unsigned g = v[0];
                    #pragma unroll
                    for (int j = 1; j < 8; ++j) g = g > v[j] ? g : v[j];
                    while (__any((int)(g > clst[9]))) {
                        const bool mine = g > clst[9];
                        if (mine) {
                            const int G = (int)(g & 31u);
                            #pragma unroll
                            for (int r4 = 0; r4 < 4; ++r4) {
                                const int row = G * 4 + r4;
                                unsigned d = *reinterpret_cast<const unsigned*>(
                                    simt + row * 256 + ((ulc ^ (row & 15)) << 4) + boc);
                                unsigned k = hi ? (d & 0xFFFF0000u) : (d << 16);
                                if (k > clst[9]) ins10(clst, k);
                            }
                        }
                        const unsigned s = mine ? g : 0u;
                        unsigned ng = 0u;
                        #pragma unroll
                        for (int j = 0; j < 8; ++j) {
                            v[j] = (v[j] == s) ? 0u : v[j];
                            ng = ng > v[j] ? ng : v[j];
                        }
                        g = ng;
                    }
                }
                #pragma unroll
                for (int q = 0; q < 10; ++q) cl[q] = clst[q];
            }
            __syncthreads();
        }

        // flush row lists for this ti band (pair-merge via shuffle)
        if (tid < 256) {
            unsigned merged[10];
            #pragma unroll
            for (int q = 0; q < 10; ++q) merged[q] = rlst[q];
            #pragma unroll
            for (int q = 0; q < 10; ++q) {
                unsigned o = (unsigned)__shfl_xor((int)rlst[q], 1);
                if (o > merged[9]) ins10(merged, o);
            }
            if (!(tid & 1)) {
                unsigned* dst = rowcand +
                    ((size_t)(i0 + ti * 128 + (tid >> 1)) * NCH + blockIdx.x) * 10;
                #pragma unroll
                for (int q = 0; q < 10; ++q) dst[q] = merged[q];
            }
            #pragma unroll
            for (int q = 0; q < 10; ++q) rlst[q] = 0u;
        }
    }

    // flush col lists
    __syncthreads();
    for (int q = tid; q < 512 * 10; q += 512) {
        int cl = q / 10, qq = q % 10;
        colcand[((size_t)(j0 + cl) * NCH + blockIdx.y) * 10 + qq] = collist[cl][qq];
    }
}

// ---------------------------------------------------------------------------
// Kernel 3: merge 32 chunks x 10 key-candidates -> mean(top10) = rt / rs
// ---------------------------------------------------------------------------
__global__ __launch_bounds__(256) void reduce_topk(
        const unsigned* __restrict__ rowcand, const unsigned* __restrict__ colcand,
        float* __restrict__ rt, float* __restrict__ rs) {
    const int t = blockIdx.x * 256 + threadIdx.x;   // 0 .. 2N-1
    const bool isRow = (t < NN);
    const int  row   = isRow ? t : t - NN;
    const unsigned* src = isRow ? rowcand : colcand;

    unsigned lst[10];
    #pragma unroll
    for (int q = 0; q < 10; ++q) lst[q] = 0u;

    const uint4* p = reinterpret_cast<const uint4*>(src + (size_t)row * (NCH * 10));
    for (int c = 0; c < NCH * 10 / 4; ++c) {
        uint4 v = p[c];
        unsigned g01 = v.x > v.y ? v.x : v.y;
        unsigned g23 = v.z > v.w ? v.z : v.w;
        unsigned gm  = g01 > g23 ? g01 : g23;
        if (gm > lst[9]) {
            if (v.x > lst[9]) ins10(lst, v.x);
            if (v.y > lst[9]) ins10(lst, v.y);
            if (v.z > lst[9]) ins10(lst, v.z);
            if (v.w > lst[9]) ins10(lst, v.w);
        }
    }
    float s = 0.f;
    #pragma unroll
    for (int q = 0; q < 10; ++q) s += key2f(lst[q]);
    s *= 0.1f;
    if (isRow) rt[row] = s; else rs[row] = s;
}

// ---------------------------------------------------------------------------
// Kernel 4: gathered dots + CSLS logits.
// ---------------------------------------------------------------------------
__global__ __launch_bounds__(256) void logits_kernel(
        const __hip_bfloat16* __restrict__ srcH, const __hip_bfloat16* __restrict__ tgtH,
        const int* __restrict__ sidx, const int* __restrict__ tidx,
        const float* __restrict__ rt, const float* __restrict__ rs,
        float* __restrict__ out) {
    const int b    = blockIdx.x;
    const int lane = threadIdx.x & 63;
    const int w    = threadIdx.x >> 6;

    const int s0 = sidx[b * KK];
    const int t0 = tidx[b * KK];
    float ps[5], pt[5];
    #pragma unroll
    for (int j = 0; j < 5; ++j) {
        int d = lane + 64 * j;
        ps[j] = __bfloat162float(srcH[(size_t)s0 * DP + d]);
        pt[j] = __bfloat162float(tgtH[(size_t)t0 * DP + d]);
    }
    const float rt_s0 = rt[s0];
    const float rs_t0 = rs[t0];

    for (int kk = w; kk < KK; kk += 4) {
        const int it = tidx[b * KK + kk];
        const int is = sidx[b * KK + kk];
        float a = 0.f, c = 0.f;
        #pragma unroll
        for (int j = 0; j < 5; ++j) {
            int d = lane + 64 * j;
            a += ps[j] * __bfloat162float(tgtH[(size_t)it * DP + d]);
            c += pt[j] * __bfloat162float(srcH[(size_t)is * DP + d]);
        }
        #pragma unroll
        for (int o = 32; o; o >>= 1) {
            a += __shfl_xor(a, o);
            c += __shfl_xor(c, o);
        }
        if (lane == 0) {
            out[b * KK + kk]           = 2.f * a - rt_s0 - rs[it];
            out[BB * KK + b * KK + kk] = 2.f * c - rs_t0 - rt[is];
        }
    }
}

// ---------------------------------------------------------------------------
extern "C" void kernel_launch(void* const* d_in, const int* in_sizes, int n_in,
                              void* d_out, int out_size, void* d_ws, size_t ws_size,
                              hipStream_t stream) {
    const float* nf_src = (const float*)d_in[0];
    const float* nf_tgt = (const float*)d_in[1];
    const int*   sidx   = (const int*)d_in[2];
    const int*   tidx   = (const int*)d_in[3];
    const float* svs    = (const float*)d_in[4];
    const float* tvs    = (const float*)d_in[5];

    char* ws = (char*)d_ws;
    const size_t SZ_H    = (size_t)NN * DP * 2;            // bf16 features
    const size_t SZ_CAND = (size_t)NN * NCH * 10 * 4;
    __hip_bfloat16* srcH = (__hip_bfloat16*)ws;
    __hip_bfloat16* tgtH = (__hip_bfloat16*)(ws + SZ_H);
    unsigned* rowcand = (unsigned*)(ws + 2 * SZ_H);
    unsigned* colcand = (unsigned*)(ws + 2 * SZ_H + SZ_CAND);
    float* rt = (float*)(ws + 2 * SZ_H + 2 * SZ_CAND);
    float* rs = (float*)(ws + 2 * SZ_H + 2 * SZ_CAND + (size_t)NN * 4);

    tower_kernel<<<NN / 4, 256, 0, stream>>>(nf_src, svs, srcH);
    tower_kernel<<<NN / 4, 256, 0, stream>>>(nf_tgt, tvs, tgtH);
    sim_topk_kernel<<<dim3(NCH, NCH), 512, 0, stream>>>(srcH, tgtH, rowcand, colcand);
    reduce_topk<<<(2 * NN) / 256, 256, 0, stream>>>(rowcand, colcand, rt, rs);
    logits_kernel<<<BB, 256, 0, stream>>>(srcH, tgtH, sidx, tidx, rt, rs, (float*)d_out);
}

// Round 6
// 682.061 us; speedup vs baseline: 1.4606x; 1.1745x over previous
//
#include <hip/hip_runtime.h>
#include <hip/hip_bf16.h>

#define NN 16384
#define DD 300
#define DP 320
#define RR 10
#define BB 1024
#define KK 64
#define NCH 32   // column/row chunks (N / 512)

typedef __attribute__((ext_vector_type(8))) short s8v;   // 8 bf16 (4 VGPRs)
typedef __attribute__((ext_vector_type(4))) float f4v;   // MFMA accumulator

// ---- monotone bf16->u16 key (order-preserving, packed 2 per dword) --------
__device__ __forceinline__ unsigned mono2(unsigned d) {
    // per u16 half: pos -> b|0x8000 ; neg -> ~b   (strictly increasing map)
    unsigned s = ((d >> 15) & 0x10001u) * 0xFFFFu;
    return d ^ (s | 0x80008000u);
}
__device__ __forceinline__ unsigned pack_mono(float a, float b) {
    __hip_bfloat16 ba = __float2bfloat16(a);
    __hip_bfloat16 bb = __float2bfloat16(b);
    unsigned ua = *reinterpret_cast<unsigned short*>(&ba);
    unsigned ub = *reinterpret_cast<unsigned short*>(&bb);
    return mono2(ua | (ub << 16));
}
__device__ __forceinline__ float key2f(unsigned k) {
    unsigned k16 = k >> 16;
    unsigned b = (k16 & 0x8000u) ? (k16 ^ 0x8000u) : (~k16 & 0xFFFFu);
    return __uint_as_float(b << 16);
}

// sorted-descending top-10 insert, unsigned keys (max/min chain)
__device__ __forceinline__ void ins10(unsigned (&lst)[10], unsigned v) {
    #pragma unroll
    for (int q = 0; q < 10; ++q) {
        unsigned a  = lst[q];
        unsigned mx = a > v ? a : v;
        v           = a > v ? v : a;
        lst[q] = mx;
    }
}

// extract-max loop over an 8-value group: wave-cheap divergence
__device__ __forceinline__ void scan8(unsigned (&v)[8], unsigned (&lst)[10]) {
    unsigned g = v[0];
    #pragma unroll
    for (int j = 1; j < 8; ++j) g = g > v[j] ? g : v[j];
    while (__any((int)(g > lst[9]))) {
        const bool mine = g > lst[9];
        if (mine) ins10(lst, g);
        const unsigned s = mine ? g : 0u;
        unsigned ng = 0u;
        #pragma unroll
        for (int j = 0; j < 8; ++j) {
            v[j] = (v[j] == s) ? 0u : v[j];
            ng = ng > v[j] ? ng : v[j];
        }
        g = ng;
    }
}

// ---------------------------------------------------------------------------
// Kernel 1: Householder tower + L2 normalize + bf16 cast (padded to 320).
// ---------------------------------------------------------------------------
__global__ __launch_bounds__(256) void tower_kernel(
        const float* __restrict__ feat, const float* __restrict__ vs,
        __hip_bfloat16* __restrict__ out) {
    __shared__ float vsh[RR * DD];
    const int tid = threadIdx.x;
    for (int i = tid; i < RR * DD; i += 256) vsh[i] = vs[i];
    __syncthreads();

    const int lane = tid & 63;
    const int wave = tid >> 6;
    const int row  = blockIdx.x * 4 + wave;

    float h[5];
    #pragma unroll
    for (int j = 0; j < 5; ++j) {
        int d = lane + 64 * j;
        h[j] = (d < DD) ? feat[(size_t)row * DD + d] : 0.f;
    }

    #pragma unroll
    for (int r = 0; r < RR; ++r) {
        float vl[5];
        float hv = 0.f, vv = 0.f;
        #pragma unroll
        for (int j = 0; j < 5; ++j) {
            int d = lane + 64 * j;
            float v = (d < DD) ? vsh[r * DD + d] : 0.f;
            vl[j] = v;
            hv += h[j] * v;
            vv += v * v;
        }
        #pragma unroll
        for (int o = 32; o; o >>= 1) {
            hv += __shfl_xor(hv, o);
            vv += __shfl_xor(vv, o);
        }
        float coef = hv / vv;
        #pragma unroll
        for (int j = 0; j < 5; ++j) h[j] -= coef * vl[j];
    }

    float nn = 0.f;
    #pragma unroll
    for (int j = 0; j < 5; ++j) nn += h[j] * h[j];
    #pragma unroll
    for (int o = 32; o; o >>= 1) nn += __shfl_xor(nn, o);
    float scale = 1.f / fmaxf(sqrtf(nn), 1e-12f);

    #pragma unroll
    for (int j = 0; j < 5; ++j) {
        int d = lane + 64 * j;
        float val = (d < DD) ? h[j] * scale : 0.f;
        out[(size_t)row * DP + d] = __float2bfloat16(val);
    }
}

// ---------------------------------------------------------------------------
// Kernel 2: 512x512 sim region per block (grid 32x32), 16 inner 128x128 MFMA
// tiles. Reg-staged LDS (swizzled writes), monotone-key sim tile, swizzled
// colmax side-tile, extract-max scans with ALL lists in LDS (u16 keys,
// 2 slots) -> no per-thread persistent arrays -> no scratch spills.
// LDS 66560 B -> 2 blocks/CU.
// ---------------------------------------------------------------------------
__global__ __launch_bounds__(512, 4) void sim_topk_kernel(
        const __hip_bfloat16* __restrict__ A,   // src_hn [N][320]
        const __hip_bfloat16* __restrict__ Bm,  // tgt_hn [N][320]
        unsigned* __restrict__ rowcand,         // [N][NCH][10] (u32 keys)
        unsigned* __restrict__ colcand) {       // [N][NCH][10] (u32 keys)
    // union: staging (Asub|Bsub [128][64] bf16, unit-swizzled) = 32768 B
    //      | simt (key-dword [128][64], unit-XOR-swizzled)
    __shared__ __align__(16) char u_lds[32768];
    __shared__ unsigned colmax[32 * 64];              // swizzled: dw ^ ((g&7)<<3)
    __shared__ unsigned short rowlist[128][2][10];    // per-ti-band, 2 slots
    __shared__ unsigned short collist[512][2][10];    // whole kernel, 2 slots

    __hip_bfloat16* Asub = (__hip_bfloat16*)u_lds;             // [128][64]
    __hip_bfloat16* Bsub = (__hip_bfloat16*)(u_lds + 16384);   // [128][64]
    char* simt = u_lds;  // dword idx d at row r -> byte r*256 + ((d>>2 ^ (r&15))<<4) + (d&3)*4

    const int tid  = threadIdx.x;
    const int lane = tid & 63;
    const int w    = tid >> 6;   // 0..7
    const int wr   = w >> 2;     // 0..1
    const int wc   = w & 3;      // 0..3
    const int i0   = blockIdx.y * 512;
    const int j0   = blockIdx.x * 512;

    for (int q = tid; q < 512 * 2 * 10; q += 512) (&collist[0][0][0])[q] = 0;
    __syncthreads();

    const int sr0 = tid >> 3, su0 = tid & 7;
    const int sp0 = (su0 ^ (sr0 & 7)) * 8;   // swizzled LDS unit offset

    for (int ti = 0; ti < 4; ++ti) {
        // init row lists for this ti band
        for (int q = tid; q < 128 * 2 * 10; q += 512) (&rowlist[0][0][0])[q] = 0;
        // (barriers inside the tj loop order this vs. first scan)

        for (int tj = 0; tj < 4; ++tj) {
            f4v acc[4][2];
            #pragma unroll
            for (int m = 0; m < 4; ++m)
                #pragma unroll
                for (int n = 0; n < 2; ++n)
                    acc[m][n] = (f4v){0.f, 0.f, 0.f, 0.f};

            const __hip_bfloat16* Ab = A  + (size_t)(i0 + ti * 128) * DP;
            const __hip_bfloat16* Bb = Bm + (size_t)(j0 + tj * 128) * DP;

            for (int kb = 0; kb < 5; ++kb) {
                __syncthreads();   // prior phase (frag reads / scan) done
                {   // reg-staged: linear global reads, swizzled LDS writes
                    const size_t go = (size_t)sr0 * DP + kb * 64 + su0 * 8;
                    int4 va0 = *reinterpret_cast<const int4*>(Ab + go);
                    int4 vb0 = *reinterpret_cast<const int4*>(Bb + go);
                    int4 va1 = *reinterpret_cast<const int4*>(Ab + go + (size_t)64 * DP);
                    int4 vb1 = *reinterpret_cast<const int4*>(Bb + go + (size_t)64 * DP);
                    *reinterpret_cast<int4*>(Asub + sr0 * 64 + sp0)        = va0;
                    *reinterpret_cast<int4*>(Bsub + sr0 * 64 + sp0)        = vb0;
                    *reinterpret_cast<int4*>(Asub + (sr0 + 64) * 64 + sp0) = va1;
                    *reinterpret_cast<int4*>(Bsub + (sr0 + 64) * 64 + sp0) = vb1;
                }
                __syncthreads();
                #pragma unroll
                for (int ks = 0; ks < 2; ++ks) {
                    s8v af[4], bfv[2];
                    const int ulog = ks * 4 + (lane >> 4);
                    const int up   = ulog ^ (lane & 7);   // row&7 == lane&7
                    #pragma unroll
                    for (int m = 0; m < 4; ++m) {
                        const int row = wr * 64 + m * 16 + (lane & 15);
                        af[m] = *reinterpret_cast<const s8v*>(Asub + row * 64 + up * 8);
                    }
                    #pragma unroll
                    for (int n = 0; n < 2; ++n) {
                        const int row = wc * 32 + n * 16 + (lane & 15);
                        bfv[n] = *reinterpret_cast<const s8v*>(Bsub + row * 64 + up * 8);
                    }
                    #pragma unroll
                    for (int m = 0; m < 4; ++m)
                        #pragma unroll
                        for (int n = 0; n < 2; ++n)
                            acc[m][n] = __builtin_amdgcn_mfma_f32_16x16x32_bf16(
                                af[m], bfv[n], acc[m][n], 0, 0, 0);
                }
            }
            __syncthreads();   // frag reads done before simt overwrites staging

            // scatter -> monotone-key dwords (lo = col, hi = col+16) + colmax
            // C/D layout: col = lane&15, row = (lane>>4)*4 + reg
            {
                const int d_idx = wc * 16 + (lane & 15);
                const int ul    = d_idx >> 2;
                const int bo    = (d_idx & 3) * 4;
                #pragma unroll
                for (int m = 0; m < 4; ++m) {
                    #pragma unroll
                    for (int r = 0; r < 4; ++r) {
                        const int rr = wr * 64 + m * 16 + (lane >> 4) * 4 + r;
                        unsigned d = pack_mono(acc[m][0][r], acc[m][1][r]);
                        *reinterpret_cast<unsigned*>(
                            simt + rr * 256 + ((ul ^ (rr & 15)) << 4) + bo) = d;
                    }
                    float m0 = fmaxf(fmaxf(acc[m][0][0], acc[m][0][1]),
                                     fmaxf(acc[m][0][2], acc[m][0][3]));
                    float m1 = fmaxf(fmaxf(acc[m][1][0], acc[m][1][1]),
                                     fmaxf(acc[m][1][2], acc[m][1][3]));
                    const int g = wr * 16 + m * 4 + (lane >> 4);
                    colmax[g * 64 + (d_idx ^ ((g & 7) << 3))] = pack_mono(m0, m1);
                }
            }
            __syncthreads();

            if (tid < 256) {
                // row scan: 2 threads/row (own u16 LDS slot), 8 units each
                const int rloc = tid >> 1;
                const int half = tid & 1;
                const char* rbase = simt + rloc * 256;
                const int sw  = rloc & 15;
                const int ub0 = half * 8;
                unsigned short* rl = rowlist[rloc][half];
                unsigned lst[10];
                #pragma unroll
                for (int q = 0; q < 10; ++q) lst[q] = (unsigned)rl[q] << 16;
                #pragma unroll
                for (int ub = 0; ub < 8; ++ub) {
                    uint4 q = *reinterpret_cast<const uint4*>(
                        rbase + (((ub0 + ub) ^ sw) << 4));
                    unsigned v[8];
                    v[0] = (q.x << 16) | 0u; v[1] = (q.x & 0xFFFF0000u) | 1u;
                    v[2] = (q.y << 16) | 2u; v[3] = (q.y & 0xFFFF0000u) | 3u;
                    v[4] = (q.z << 16) | 4u; v[5] = (q.z & 0xFFFF0000u) | 5u;
                    v[6] = (q.w << 16) | 6u; v[7] = (q.w & 0xFFFF0000u) | 7u;
                    scan8(v, lst);
                }
                #pragma unroll
                for (int q = 0; q < 10; ++q) rl[q] = (unsigned short)(lst[q] >> 16);
            } else {
                // col scan: 2 threads/col (own slot), 2 rowgroup-blocks each
                const int idx  = tid - 256;      // 0..255
                const int c    = idx & 127;
                const int half = idx >> 7;
                const int dw   = (c >> 5) * 16 + (c & 15);
                const int hi   = (c >> 4) & 1;
                const int ulc  = dw >> 2;
                const int boc  = (dw & 3) * 4;
                unsigned short* cl = collist[tj * 128 + c][half];
                unsigned clst[10];
                #pragma unroll
                for (int q = 0; q < 10; ++q) clst[q] = (unsigned)cl[q] << 16;
                #pragma unroll
                for (int gbl = 0; gbl < 2; ++gbl) {
                    const int gb = half * 2 + gbl;
                    unsigned v[8];
                    #pragma unroll
                    for (int j = 0; j < 8; ++j) {
                        const int g = gb * 8 + j;
                        unsigned d = colmax[g * 64 + (dw ^ ((g & 7) << 3))];
                        unsigned k16 = hi ? (d >> 16) : (d & 0xFFFFu);
                        v[j] = (k16 << 16) | (unsigned)g;
                    }
                    unsigned g = v[0];
                    #pragma unroll
                    for (int j = 1; j < 8; ++j) g = g > v[j] ? g : v[j];
                    while (__any((int)(g > clst[9]))) {
                        const bool mine = g > clst[9];
                        if (mine) {
                            const int G = (int)(g & 31u);
                            #pragma unroll
                            for (int r4 = 0; r4 < 4; ++r4) {
                                const int row = G * 4 + r4;
                                unsigned d = *reinterpret_cast<const unsigned*>(
                                    simt + row * 256 + ((ulc ^ (row & 15)) << 4) + boc);
                                unsigned k = hi ? (d & 0xFFFF0000u) : (d << 16);
                                if (k > clst[9]) ins10(clst, k);
                            }
                        }
                        const unsigned s = mine ? g : 0u;
                        unsigned ng = 0u;
                        #pragma unroll
                        for (int j = 0; j < 8; ++j) {
                            v[j] = (v[j] == s) ? 0u : v[j];
                            ng = ng > v[j] ? ng : v[j];
                        }
                        g = ng;
                    }
                }
                #pragma unroll
                for (int q = 0; q < 10; ++q) cl[q] = (unsigned short)(clst[q] >> 16);
            }
            __syncthreads();
        }

        // flush row lists for this ti band (merge 2 slots)
        if (tid < 128) {
            unsigned lst[10];
            #pragma unroll
            for (int q = 0; q < 10; ++q) lst[q] = (unsigned)rowlist[tid][0][q] << 16;
            #pragma unroll
            for (int q = 0; q < 10; ++q) {
                unsigned v = (unsigned)rowlist[tid][1][q] << 16;
                if (v > lst[9]) ins10(lst, v);
            }
            unsigned* dst = rowcand +
                ((size_t)(i0 + ti * 128 + tid) * NCH + blockIdx.x) * 10;
            #pragma unroll
            for (int q = 0; q < 10; ++q) dst[q] = lst[q];
        }
        __syncthreads();   // flush reads done before next band's re-init
    }

    // flush col lists (merge 2 slots), one col per thread
    {
        const int c = tid;   // 0..511
        unsigned lst[10];
        #pragma unroll
        for (int q = 0; q < 10; ++q) lst[q] = (unsigned)collist[c][0][q] << 16;
        #pragma unroll
        for (int q = 0; q < 10; ++q) {
            unsigned v = (unsigned)collist[c][1][q] << 16;
            if (v > lst[9]) ins10(lst, v);
        }
        unsigned* dst = colcand + ((size_t)(j0 + c) * NCH + blockIdx.y) * 10;
        #pragma unroll
        for (int q = 0; q < 10; ++q) dst[q] = lst[q];
    }
}

// ---------------------------------------------------------------------------
// Kernel 3: merge 32 chunks x 10 key-candidates -> mean(top10) = rt / rs
// ---------------------------------------------------------------------------
__global__ __launch_bounds__(256) void reduce_topk(
        const unsigned* __restrict__ rowcand, const unsigned* __restrict__ colcand,
        float* __restrict__ rt, float* __restrict__ rs) {
    const int t = blockIdx.x * 256 + threadIdx.x;   // 0 .. 2N-1
    const bool isRow = (t < NN);
    const int  row   = isRow ? t : t - NN;
    const unsigned* src = isRow ? rowcand : colcand;

    unsigned lst[10];
    #pragma unroll
    for (int q = 0; q < 10; ++q) lst[q] = 0u;

    const uint4* p = reinterpret_cast<const uint4*>(src + (size_t)row * (NCH * 10));
    for (int c = 0; c < NCH * 10 / 4; ++c) {
        uint4 v = p[c];
        unsigned g01 = v.x > v.y ? v.x : v.y;
        unsigned g23 = v.z > v.w ? v.z : v.w;
        unsigned gm  = g01 > g23 ? g01 : g23;
        if (gm > lst[9]) {
            if (v.x > lst[9]) ins10(lst, v.x);
            if (v.y > lst[9]) ins10(lst, v.y);
            if (v.z > lst[9]) ins10(lst, v.z);
            if (v.w > lst[9]) ins10(lst, v.w);
        }
    }
    float s = 0.f;
    #pragma unroll
    for (int q = 0; q < 10; ++q) s += key2f(lst[q]);
    s *= 0.1f;
    if (isRow) rt[row] = s; else rs[row] = s;
}

// ---------------------------------------------------------------------------
// Kernel 4: gathered dots + CSLS logits.
// ---------------------------------------------------------------------------
__global__ __launch_bounds__(256) void logits_kernel(
        const __hip_bfloat16* __restrict__ srcH, const __hip_bfloat16* __restrict__ tgtH,
        const int* __restrict__ sidx, const int* __restrict__ tidx,
        const float* __restrict__ rt, const float* __restrict__ rs,
        float* __restrict__ out) {
    const int b    = blockIdx.x;
    const int lane = threadIdx.x & 63;
    const int w    = threadIdx.x >> 6;

    const int s0 = sidx[b * KK];
    const int t0 = tidx[b * KK];
    float ps[5], pt[5];
    #pragma unroll
    for (int j = 0; j < 5; ++j) {
        int d = lane + 64 * j;
        ps[j] = __bfloat162float(srcH[(size_t)s0 * DP + d]);
        pt[j] = __bfloat162float(tgtH[(size_t)t0 * DP + d]);
    }
    const float rt_s0 = rt[s0];
    const float rs_t0 = rs[t0];

    for (int kk = w; kk < KK; kk += 4) {
        const int it = tidx[b * KK + kk];
        const int is = sidx[b * KK + kk];
        float a = 0.f, c = 0.f;
        #pragma unroll
        for (int j = 0; j < 5; ++j) {
            int d = lane + 64 * j;
            a += ps[j] * __bfloat162float(tgtH[(size_t)it * DP + d]);
            c += pt[j] * __bfloat162float(srcH[(size_t)is * DP + d]);
        }
        #pragma unroll
        for (int o = 32; o; o >>= 1) {
            a += __shfl_xor(a, o);
            c += __shfl_xor(c, o);
        }
        if (lane == 0) {
            out[b * KK + kk]           = 2.f * a - rt_s0 - rs[it];
            out[BB * KK + b * KK + kk] = 2.f * c - rs_t0 - rt[is];
        }
    }
}

// ---------------------------------------------------------------------------
extern "C" void kernel_launch(void* const* d_in, const int* in_sizes, int n_in,
                              void* d_out, int out_size, void* d_ws, size_t ws_size,
                              hipStream_t stream) {
    const float* nf_src = (const float*)d_in[0];
    const float* nf_tgt = (const float*)d_in[1];
    const int*   sidx   = (const int*)d_in[2];
    const int*   tidx   = (const int*)d_in[3];
    const float* svs    = (const float*)d_in[4];
    const float* tvs    = (const float*)d_in[5];

    char* ws = (char*)d_ws;
    const size_t SZ_H    = (size_t)NN * DP * 2;            // bf16 features
    const size_t SZ_CAND = (size_t)NN * NCH * 10 * 4;
    __hip_bfloat16* srcH = (__hip_bfloat16*)ws;
    __hip_bfloat16* tgtH = (__hip_bfloat16*)(ws + SZ_H);
    unsigned* rowcand = (unsigned*)(ws + 2 * SZ_H);
    unsigned* colcand = (unsigned*)(ws + 2 * SZ_H + SZ_CAND);
    float* rt = (float*)(ws + 2 * SZ_H + 2 * SZ_CAND);
    float* rs = (float*)(ws + 2 * SZ_H + 2 * SZ_CAND + (size_t)NN * 4);

    tower_kernel<<<NN / 4, 256, 0, stream>>>(nf_src, svs, srcH);
    tower_kernel<<<NN / 4, 256, 0, stream>>>(nf_tgt, tvs, tgtH);
    sim_topk_kernel<<<dim3(NCH, NCH), 512, 0, stream>>>(srcH, tgtH, rowcand, colcand);
    reduce_topk<<<(2 * NN) / 256, 256, 0, stream>>>(rowcand, colcand, rt, rs);
    logits_kernel<<<BB, 256, 0, stream>>>(srcH, tgtH, sidx, tidx, rt, rs, (float*)d_out);
}